// Round 2
// 407.643 us; speedup vs baseline: 1.1443x; 1.1443x over previous
//
#include <hip/hip_runtime.h>
#include <stdint.h>

// MinkFormerBlock on MI355X (gfx950). I/O: f32 in, f32 out (verified R8).
// R15: 4-deep half-K ring with EXACT counted vmcnt. R14 crashed: idx
// register copies raced pending asm loads, and idx loads broke the vmcnt
// stage accounting. Now: stage = (tap, K-half) = A 16KB + B 16KB = 32 KB,
// 4-buffer ring in 128 KB LDS. Main loop 4-unrolled so the two idx register
// sets (idxA=even taps, idxB=odd taps) are STATICALLY selected (no copies,
// no dynamic indexing). Issue order is deterministic; per-iteration wait is
// s_waitcnt vmcnt(20) lgkmcnt(0) (exact: stage s has >=20 ops after it, idx
// uses have exactly 20 ops after their load), epilogue 20,16,16,16,8,0.
// lgkmcnt(0) before each raw s_barrier drains ds_reads (buffer WAR safety);
// sched_barrier(0) after each barrier pins consumers after their wait.
//
//   cvt:       xb = bf16(x)            (aliases h_b, dead until ew1)
//   wt:        WT* = bf16(W^T)  [tap][Cout][Cin]
//   gg<1,0>:   a = xb @ Wa1 ; v = xb @ Wv1     (bf16)
//   gg<125,1>: g = gather(a,nbr5)@W5 * v       (bf16, fused gate)
//   gg<27,2>:  t = gather(g,nbr3a)@W31         (f32)
//   bn+fin -> sc1,sh1 ; ew1: res=bf16->g_b, h=bf16(relu)->h_b
//   gg<27,2>:  t2 = gather(h,nbr3b)@W32        (f32)
//   bn+fin -> sc2,sh2 ; ew2: d_out = relu(t2*sc+sh + res)  (f32)

#define NPTS 32768
#define C 128
#define EPS 1e-5f

typedef unsigned short u16;
using bfrag = __attribute__((ext_vector_type(8))) short;   // 8 bf16 = 4 VGPRs
using f32x4 = __attribute__((ext_vector_type(4))) float;

__device__ __forceinline__ float b2f(u16 u) {
  union { unsigned int i; float f; } x;
  x.i = ((unsigned int)u) << 16;
  return x.f;
}
__device__ __forceinline__ u16 f2b(float f) {
  union { float f; unsigned int i; } x;
  x.f = f;
  unsigned int r = x.i + 0x7FFFu + ((x.i >> 16) & 1u);   // RNE
  return (u16)(r >> 16);
}

// async global->LDS, 16 B per lane; LDS dest is wave-uniform base + lane*16.
__device__ __forceinline__ void g2l16(const void* g, void* l) {
  __builtin_amdgcn_global_load_lds(
      (const __attribute__((address_space(1))) unsigned int*)g,
      (__attribute__((address_space(3))) unsigned int*)l,
      16, 0, 0);
}

// wait (exact vmcnt + full lgkm drain) -> barrier -> scheduling fence.
#define GG_WAITB(N)                                                        \
  asm volatile("s_waitcnt vmcnt(" #N ") lgkmcnt(0)" ::: "memory");         \
  __builtin_amdgcn_s_barrier();                                            \
  __builtin_amdgcn_sched_barrier(0)

// =====================================================================
// Gather-GEMM, 4-stage half-K ring. Block = 128x128, 4 waves (2x2), wave =
// 64x64 via 4x4 mfma_f32_16x16x32_bf16.
// Stage s = (tap s>>1, half s&1): A-half [0,16K) = 128 rows x 128 B,
// B-half [16K,32K), in buffer (s&3)*32KB. Wave w stages rows [w*32,+32):
// 4 DMA instrs A + 4 B (1 KB = 8 rows x 128 B each). Global-side XOR chunk
// swizzle (lane r8,cs8 fetches global chunk cs8^r8 into slot cs8; row&7 ==
// r8) so ds_read_b128 at slot (kk*4+lsub)^(row&7) is 2-way-aliased (free).
// Iter s: wait(exact) -> barrier -> issue stage s+3 into buf (s+3)&3 ->
// compute stage s (2 k-steps x 16 MFMA). Loads span barriers; vmcnt never
// drains mid-loop. Idx loads via inline asm (invisible to the waitcnt pass;
// guarded by the manual waits, >=20 ops after every load before use).
// EPI: 0 bf16 out; 1 bf16(acc*vmul); 2 f32 out.
// =====================================================================
template <int NTAPS, int EPI>
__global__ __launch_bounds__(256)
void gg_kernel(const u16* __restrict__ src, const u16* __restrict__ WT,
               const int* __restrict__ nbr, u16* __restrict__ outb,
               float* __restrict__ outf, const u16* __restrict__ vmul) {
  __shared__ uint4 lds[8192];          // 128 KB: four 32 KB stage buffers
  char* const base = (char*)lds;
  constexpr int S = NTAPS * 2;         // half-K stages (== 2 mod 4 for odd NTAPS)

  const int tid  = threadIdx.x;
  const int lane = tid & 63;
  const int wave = tid >> 6;
  const int wr   = wave >> 1, wc = wave & 1;
  const int lsub = lane >> 4, lm = lane & 15;
  const int row0 = blockIdx.x * 128;
  const int r8   = lane >> 3;          // row within a DMA instr (0..7)
  const int cs8  = lane & 7;           // chunk slot (0..7, 16 B each)

  f32x4 acc[4][4];
#pragma unroll
  for (int i = 0; i < 4; i++)
#pragma unroll
    for (int j = 0; j < 4; j++) acc[i][j] = (f32x4)(0.0f);

  // idx loads via asm: the compiler's waitcnt pass must not see them (it
  // would insert conservative waits); manual waits guarantee completion.
  auto loadIdx = [&](int (&d)[4], int t) {
#pragma unroll
    for (int j = 0; j < 4; j++) {
      const int gr = row0 + wave * 32 + j * 8 + r8;
      const int* p = nbr + (size_t)gr * NTAPS + t;
      asm volatile("global_load_dword %0, %1, off"
                   : "=v"(d[j]) : "v"(p) : "memory");
    }
  };

  auto stageA = [&](char* nb, const int (&id)[4], int h) {
#pragma unroll
    for (int j = 0; j < 4; j++) {
      const char* gp = (const char*)src + ((size_t)(unsigned)id[j] << 8)
                     + (h << 7) + ((cs8 ^ r8) << 4);
      g2l16(gp, nb + (wave * 32 + j * 8) * 128);
    }
  };
  auto stageB = [&](char* nb, int t, int h) {
    const char* wt = (const char*)WT + ((size_t)t << 15) + (h << 7);
#pragma unroll
    for (int j = 0; j < 4; j++) {
      const int col = wave * 32 + j * 8 + r8;
      g2l16(wt + ((size_t)col << 8) + ((cs8 ^ r8) << 4),
            nb + 16384 + (wave * 32 + j * 8) * 128);
    }
  };

  // compute one stage (2 k-steps of 32) from buffer cbuf
  auto compute = [&](const char* cbuf) {
    const char* sA = cbuf;
    const char* sB = cbuf + 16384;
#pragma unroll
    for (int kk = 0; kk < 2; kk++) {
      bfrag af[4], bg[4];
#pragma unroll
      for (int rt = 0; rt < 4; rt++) {
        const int row = wr * 64 + rt * 16 + lm;
        af[rt] = *(const bfrag*)(sA + row * 128
                                 + (((kk * 4 + lsub) ^ (row & 7)) << 4));
      }
#pragma unroll
      for (int ct = 0; ct < 4; ct++) {
        const int col = wc * 64 + ct * 16 + lm;
        bg[ct] = *(const bfrag*)(sB + col * 128
                                 + (((kk * 4 + lsub) ^ (col & 7)) << 4));
      }
#pragma unroll
      for (int rt = 0; rt < 4; rt++)
#pragma unroll
        for (int ct = 0; ct < 4; ct++)
          acc[rt][ct] = __builtin_amdgcn_mfma_f32_16x16x32_bf16(
              af[rt], bg[ct], acc[rt][ct], 0, 0, 0);
    }
  };

  if constexpr (NTAPS == 1) {
    int idv[4];
#pragma unroll
    for (int j = 0; j < 4; j++) idv[j] = row0 + wave * 32 + j * 8 + r8;
    stageA(base, idv, 0);          stageB(base, 0, 0);          // S0
    stageA(base + 32768, idv, 1);  stageB(base + 32768, 0, 1);  // S1
    GG_WAITB(8);                   // S0 landed (8 ops after), S1 in flight
    compute(base);
    GG_WAITB(0);
    compute(base + 32768);
  } else {
    // ---- prologue: idx taps 0,1 -> wait 0 -> S0,S1 (tap0), idx tap2, S2
    int idxA[4], idxB[4];          // even-tap set / odd-tap set
    loadIdx(idxA, 0);
    loadIdx(idxB, 1);
    asm volatile("s_waitcnt vmcnt(0)" ::: "memory");
    __builtin_amdgcn_sched_barrier(0);
    stageA(base, idxA, 0);          stageB(base, 0, 0);          // S0 -> buf0
    stageA(base + 32768, idxA, 1);  stageB(base + 32768, 0, 1);  // S1 -> buf1
    loadIdx(idxA, 2);               // tap2 -> A (after S0,S1 consumed tap0)
    stageA(base + 65536, idxB, 0);  stageB(base + 65536, 1, 0);  // S2 -> buf2

    // ---- main loop: 4 sub-iters per block; set parity static per offset.
    // offset0: issue sp=s+3 (tapO=s/2+1, odd->B, h1) -> buf3, load tapO+2->B,
    //          compute buf0
    // offset1: issue sp=s+4 (tapO+1, even->A, h0) -> buf0, compute buf1
    // offset2: issue sp=s+5 (tapO+1, A, h1) -> buf1, load tapO+3->A,
    //          compute buf2
    // offset3: issue sp=s+6 (tapO+2, B, h0) -> buf2, compute buf3
#pragma unroll 1
    for (int s = 0; s < S - 6; s += 4) {
      const int tapO = (s >> 1) + 1;
      GG_WAITB(20);
      stageA(base + 98304, idxB, 1);  stageB(base + 98304, tapO, 1);
      loadIdx(idxB, tapO + 2);
      compute(base);
      GG_WAITB(20);
      stageA(base, idxA, 0);          stageB(base, tapO + 1, 0);
      compute(base + 32768);
      GG_WAITB(20);
      stageA(base + 32768, idxA, 1);  stageB(base + 32768, tapO + 1, 1);
      loadIdx(idxA, tapO + 3);
      compute(base + 65536);
      GG_WAITB(20);
      stageA(base + 65536, idxB, 0);  stageB(base + 65536, tapO + 2, 0);
      compute(base + 98304);
    }

    // ---- epilogue: s = S-6..S-1 (fixed shape, no more idx loads)
    {
      const int tN = NTAPS - 1;      // even -> set A; tN-1 odd -> set B
      GG_WAITB(20);                  // stage S-6 landed (20 ops after)
      stageA(base + 98304, idxB, 1);  stageB(base + 98304, tN - 1, 1);
      compute(base);
      GG_WAITB(16);                  // also guarantees idxA (tap tN) landed
      stageA(base, idxA, 0);          stageB(base, tN, 0);
      compute(base + 32768);
      GG_WAITB(16);
      stageA(base + 32768, idxA, 1);  stageB(base + 32768, tN, 1);
      compute(base + 65536);
      GG_WAITB(16);
      compute(base + 98304);
      GG_WAITB(8);
      compute(base);
      GG_WAITB(0);
      compute(base + 32768);
    }
  }

  // ---- epilogue write. C/D: col = lane&15, row = quad*4 + reg.
#pragma unroll
  for (int rt = 0; rt < 4; rt++) {
    const int rowb = row0 + wr * 64 + rt * 16 + lsub * 4;
#pragma unroll
    for (int ct = 0; ct < 4; ct++) {
      const int c = wc * 64 + ct * 16 + lm;
#pragma unroll
      for (int reg = 0; reg < 4; reg++) {
        const size_t off = (size_t)(rowb + reg) * C + c;
        const float v = acc[rt][ct][reg];
        if (EPI == 0)      outb[off] = f2b(v);
        else if (EPI == 1) outb[off] = f2b(v * b2f(vmul[off]));
        else               outf[off] = v;
      }
    }
  }
}

// ---- f32 -> bf16 bulk convert (for x) ------------------------------------
__global__ __launch_bounds__(256)
void cvt_kernel(const float* __restrict__ x, u16* __restrict__ xb) {
  const int i = (blockIdx.x * 256 + threadIdx.x) * 4;
  const float4 v = *(const float4*)(x + i);
  ushort4 o;
  o.x = f2b(v.x); o.y = f2b(v.y); o.z = f2b(v.z); o.w = f2b(v.w);
  *(ushort4*)(xb + i) = o;
}

// ---- weights: f32 [..,Cin,Cout] -> bf16 [..,Cout,Cin] --------------------
__global__ __launch_bounds__(256)
void wt_kernel(const float* __restrict__ W5, const float* __restrict__ W31,
               const float* __restrict__ W32, const float* __restrict__ Wa1,
               const float* __restrict__ Wv1,
               u16* __restrict__ T5, u16* __restrict__ T31, u16* __restrict__ T32,
               u16* __restrict__ Ta1, u16* __restrict__ Tv1) {
  const int b = blockIdx.x;
  const float* w;
  u16* o;
  if (b < 125)       { w = W5  + (size_t)b * 16384;         o = T5  + (size_t)b * 16384; }
  else if (b < 152)  { w = W31 + (size_t)(b - 125) * 16384; o = T31 + (size_t)(b - 125) * 16384; }
  else if (b < 179)  { w = W32 + (size_t)(b - 152) * 16384; o = T32 + (size_t)(b - 152) * 16384; }
  else if (b == 179) { w = Wa1; o = Ta1; }
  else               { w = Wv1; o = Tv1; }
  __shared__ u16 tile[128 * 129];
  for (int i = threadIdx.x; i < C * C; i += 256)
    tile[(i & 127) * 129 + (i >> 7)] = f2b(w[i]);
  __syncthreads();
  for (int i = threadIdx.x; i < C * C; i += 256)
    o[i] = tile[(i >> 7) * 129 + (i & 127)];
}

// ---- BN partials (f32): block b owns rows [b*128, +128) ------------------
__global__ __launch_bounds__(256)
void bnp_kernel(const float* __restrict__ t, float* __restrict__ psum,
                float* __restrict__ psq) {
  const int b = blockIdx.x;
  const int c = threadIdx.x & 127;
  const int h = threadIdx.x >> 7;
  const float* p = t + (size_t)(b * 128 + h * 64) * C + c;
  float s = 0.f, q = 0.f;
#pragma unroll 8
  for (int j = 0; j < 64; j++) {
    const float v = p[(size_t)j * C];
    s += v; q += v * v;
  }
  __shared__ float ls[256], lq[256];
  ls[threadIdx.x] = s; lq[threadIdx.x] = q;
  __syncthreads();
  if (h == 0) {
    psum[b * 128 + c] = ls[c] + ls[c + 128];
    psq[b * 128 + c]  = lq[c] + lq[c + 128];
  }
}

// ---- bnfin: block c reduces 256 partials (parallel; was 1-block serial) --
__global__ __launch_bounds__(256)
void bnfin_kernel(const float* __restrict__ psum, const float* __restrict__ psq,
                  const float* __restrict__ gamma, const float* __restrict__ beta,
                  float* __restrict__ scale, float* __restrict__ shift) {
  const int c = blockIdx.x;
  const int t = threadIdx.x;
  float s = psum[(size_t)t * 128 + c];
  float q = psq[(size_t)t * 128 + c];
#pragma unroll
  for (int o = 32; o > 0; o >>= 1) {
    s += __shfl_down(s, o);
    q += __shfl_down(q, o);
  }
  __shared__ float ls[4], lq[4];
  if ((t & 63) == 0) { ls[t >> 6] = s; lq[t >> 6] = q; }
  __syncthreads();
  if (t == 0) {
    s = ls[0] + ls[1] + ls[2] + ls[3];
    q = lq[0] + lq[1] + lq[2] + lq[3];
    const float mean = s * (1.0f / NPTS);
    const float var  = q * (1.0f / NPTS) - mean * mean;
    const float sc   = rsqrtf(var + EPS) * gamma[c];
    scale[c] = sc;
    shift[c] = beta[c] - mean * sc;
  }
}

// ---- ew1: o = t*sc+sh + x; res=bf16(o); h=bf16(relu o) -------------------
__global__ __launch_bounds__(256)
void ew1_kernel(const float* __restrict__ t, const float* __restrict__ x,
                const float* __restrict__ scale, const float* __restrict__ shift,
                u16* __restrict__ res, u16* __restrict__ h) {
  const int i = blockIdx.x * 256 + threadIdx.x;
  const int c = i & 127;
  const float o = t[i] * scale[c] + shift[c] + x[i];
  res[i] = f2b(o);
  h[i] = f2b(o < 0.f ? 0.f : o);
}

// ---- ew2: y = relu(t2*sc+sh + res) -> f32 d_out --------------------------
__global__ __launch_bounds__(256)
void ew2_kernel(const float* __restrict__ t2, const u16* __restrict__ res,
                const float* __restrict__ scale, const float* __restrict__ shift,
                float* __restrict__ y) {
  const int i = blockIdx.x * 256 + threadIdx.x;
  const int c = i & 127;
  const float o = t2[i] * scale[c] + shift[c] + b2f(res[i]);
  y[i] = o < 0.f ? 0.f : o;
}

// =====================================================================
extern "C" void kernel_launch(void* const* d_in, const int* in_sizes, int n_in,
                              void* d_out, int out_size, void* d_ws, size_t ws_size,
                              hipStream_t stream) {
  (void)in_sizes; (void)n_in; (void)out_size; (void)ws_size;

  const float* x   = (const float*)d_in[0];
  const float* Wa1 = (const float*)d_in[1];
  const float* Wv1 = (const float*)d_in[2];
  const float* W5  = (const float*)d_in[3];
  const float* W31 = (const float*)d_in[4];
  const float* W32 = (const float*)d_in[5];
  const float* g1  = (const float*)d_in[6];
  const float* b1  = (const float*)d_in[7];
  const float* g2  = (const float*)d_in[8];
  const float* b2  = (const float*)d_in[9];
  const int* nbr5  = (const int*)d_in[10];
  const int* nbr3a = (const int*)d_in[11];
  const int* nbr3b = (const int*)d_in[12];

  // ---- workspace (~39.8 MB) ----
  char* w = (char*)d_ws;
  u16* WT5  = (u16*)w; w += 4096000;
  u16* WT31 = (u16*)w; w += 884736;
  u16* WT32 = (u16*)w; w += 884736;
  u16* WTa1 = (u16*)w; w += 32768;
  u16* WTv1 = (u16*)w; w += 32768;
  char* AV  = w;       w += 16777216;          // a | v ; later t/t2 (f32)
  u16*   a_b = (u16*)AV;
  u16*   v_b = (u16*)(AV + 8388608);
  float* tf  = (float*)AV;
  u16* g_b  = (u16*)w; w += 8388608;           // g ; later res (bf16)
  u16* h_b  = (u16*)w; w += 8388608;           // xb first, then h (bf16)
  u16* xb   = h_b;                             // alias: xb dead before ew1
  float* psum = (float*)w; w += 131072;
  float* psq  = (float*)w; w += 131072;
  float* sc1  = (float*)w; w += 512;
  float* sh1  = (float*)w; w += 512;
  float* sc2  = (float*)w; w += 512;
  float* sh2  = (float*)w; w += 512;

  const dim3 B256(256), GG(NPTS / 128), GBN(256), GEW(NPTS * C / 256);
  float* yout = (float*)d_out;

  cvt_kernel<<<dim3(NPTS * C / 1024), B256, 0, stream>>>(x, xb);
  wt_kernel<<<dim3(181), B256, 0, stream>>>(W5, W31, W32, Wa1, Wv1,
                                            WT5, WT31, WT32, WTa1, WTv1);

  // a = xb @ Wa1 ; v = xb @ Wv1
  gg_kernel<1, 0><<<GG, B256, 0, stream>>>(xb, WTa1, nullptr, a_b, nullptr, nullptr);
  gg_kernel<1, 0><<<GG, B256, 0, stream>>>(xb, WTv1, nullptr, v_b, nullptr, nullptr);

  // g = gather125(a)@W5 * v
  gg_kernel<125, 1><<<GG, B256, 0, stream>>>(a_b, WT5, nbr5, g_b, nullptr, v_b);

  // t = gather27(g)@W31 -> f32 over AV (a,v dead)
  gg_kernel<27, 2><<<GG, B256, 0, stream>>>(g_b, WT31, nbr3a, nullptr, tf, nullptr);
  bnp_kernel<<<GBN, B256, 0, stream>>>(tf, psum, psq);
  bnfin_kernel<<<dim3(128), B256, 0, stream>>>(psum, psq, g1, b1, sc1, sh1);
  ew1_kernel<<<GEW, B256, 0, stream>>>(tf, x, sc1, sh1, g_b, h_b);   // res->g_b, h->h_b (xb dead)

  // t2 = gather27(h)@W32 -> f32 over AV (t dead)
  gg_kernel<27, 2><<<GG, B256, 0, stream>>>(h_b, WT32, nbr3b, nullptr, tf, nullptr);
  bnp_kernel<<<GBN, B256, 0, stream>>>(tf, psum, psq);
  bnfin_kernel<<<dim3(128), B256, 0, stream>>>(psum, psq, g2, b2, sc2, sh2);
  ew2_kernel<<<GEW, B256, 0, stream>>>(tf, g_b, sc2, sh2, yout);
}